// Round 4
// baseline (154.879 us; speedup 1.0000x reference)
//
#include <hip/hip_runtime.h>

// ---- prep: pad x_s rows 10->16 floats (64B, one cache line) and x_t rows 5->8 (32B) ----
__global__ __launch_bounds__(256) void pad_tables(const float* __restrict__ xs,
                                                  const float* __restrict__ xt,
                                                  float* __restrict__ xs_pad,
                                                  float* __restrict__ xt_pad,
                                                  int n_s5, int n_t5) {
    int i = blockIdx.x * 256 + threadIdx.x;
    if (i < n_s5) {            // n_s5 = N_S*5 float2 elements
        int row = i / 5, col = i % 5;
        ((float2*)xs_pad)[row * 8 + col] = ((const float2*)xs)[i];
    }
    if (i < n_t5) {            // n_t5 = N_T*5 float elements
        int row = i / 5, col = i % 5;
        xt_pad[row * 8 + col] = xt[i];
    }
}

template<bool PADDED>
__global__ __launch_bounds__(256) void edge_mlp(
    const float* __restrict__ xs,   // PADDED: 16-float rows, else 10
    const float* __restrict__ xt,   // PADDED: 8-float rows, else 5
    const int* __restrict__ src,
    const int* __restrict__ tgt,
    const float* __restrict__ ea,
    const float* __restrict__ u,
    const int* __restrict__ be,
    const float* __restrict__ W1,
    const float* __restrict__ b1,
    const float* __restrict__ W2,
    const float* __restrict__ b2,
    float* __restrict__ out, int E)
{
    __shared__ float sUp[16 * 12];    // U' = u @ W1[25:35] + b1, padded rows

    const int t = threadIdx.x;
    if (t < 160) {
        const int b = t / 10, j = t % 10;
        float acc = b1[j];
        #pragma unroll
        for (int k = 0; k < 10; ++k) acc += u[b * 10 + k] * W1[(25 + k) * 10 + j];
        sUp[b * 12 + j] = acc;
    }
    __syncthreads();

    // two edges per lane: e0 = base+t, e1 = base+t+256 (both coalesced per wave)
    const int e0 = blockIdx.x * 512 + t;
    const int e1 = e0 + 256;
    const int c0 = (e0 < E) ? e0 : (E - 1);   // clamp: branch-free loads, guarded stores
    const int c1 = (e1 < E) ? e1 : (E - 1);

    // ---- index loads (start both dependent chains immediately) ----
    const int is0 = src[c0], it0 = tgt[c0], ib0 = be[c0];
    const int is1 = src[c1], it1 = tgt[c1], ib1 = be[c1];

    // ---- gather features for both edges ----
    float f0[25], f1[25];
    if (PADDED) {
        {
            const float4* p = (const float4*)xs + (size_t)is0 * 4;   // one 64B line
            float4 a = p[0], b = p[1];
            float2 c = ((const float2*)xs)[(size_t)is0 * 8 + 4];
            f0[0] = a.x; f0[1] = a.y; f0[2] = a.z; f0[3] = a.w;
            f0[4] = b.x; f0[5] = b.y; f0[6] = b.z; f0[7] = b.w;
            f0[8] = c.x; f0[9] = c.y;
        }
        {
            const float4* p = (const float4*)xs + (size_t)is1 * 4;
            float4 a = p[0], b = p[1];
            float2 c = ((const float2*)xs)[(size_t)is1 * 8 + 4];
            f1[0] = a.x; f1[1] = a.y; f1[2] = a.z; f1[3] = a.w;
            f1[4] = b.x; f1[5] = b.y; f1[6] = b.z; f1[7] = b.w;
            f1[8] = c.x; f1[9] = c.y;
        }
        {
            const float4* q = (const float4*)xt + (size_t)it0 * 2;   // 32B row
            float4 d = q[0];
            float  d4 = xt[(size_t)it0 * 8 + 4];
            f0[10] = d.x; f0[11] = d.y; f0[12] = d.z; f0[13] = d.w; f0[14] = d4;
        }
        {
            const float4* q = (const float4*)xt + (size_t)it1 * 2;
            float4 d = q[0];
            float  d4 = xt[(size_t)it1 * 8 + 4];
            f1[10] = d.x; f1[11] = d.y; f1[12] = d.z; f1[13] = d.w; f1[14] = d4;
        }
    } else {
        const float* ps0 = xs + (size_t)is0 * 10;
        const float* ps1 = xs + (size_t)is1 * 10;
        #pragma unroll
        for (int i = 0; i < 5; ++i) {
            float2 a = *(const float2*)(ps0 + 2 * i);
            float2 b = *(const float2*)(ps1 + 2 * i);
            f0[2 * i] = a.x; f0[2 * i + 1] = a.y;
            f1[2 * i] = b.x; f1[2 * i + 1] = b.y;
        }
        const float* pt0 = xt + (size_t)it0 * 5;
        const float* pt1 = xt + (size_t)it1 * 5;
        #pragma unroll
        for (int i = 0; i < 5; ++i) { f0[10 + i] = pt0[i]; f1[10 + i] = pt1[i]; }
    }
    {
        const float2* pe0 = (const float2*)(ea + (size_t)c0 * 10);
        const float2* pe1 = (const float2*)(ea + (size_t)c1 * 10);
        #pragma unroll
        for (int i = 0; i < 5; ++i) {
            float2 a = pe0[i], b = pe1[i];
            f0[15 + 2 * i] = a.x; f0[16 + 2 * i] = a.y;
            f1[15 + 2 * i] = b.x; f1[16 + 2 * i] = b.y;
        }
    }

    // ---- layer 1: h = U'[ib] + f @ W1[0:25]; one s_load weight stream, two FMA streams ----
    float h0[10], h1[10];
    {
        float4 a = *(const float4*)&sUp[ib0 * 12];
        float4 b = *(const float4*)&sUp[ib0 * 12 + 4];
        float2 c = *(const float2*)&sUp[ib0 * 12 + 8];
        h0[0] = a.x; h0[1] = a.y; h0[2] = a.z; h0[3] = a.w;
        h0[4] = b.x; h0[5] = b.y; h0[6] = b.z; h0[7] = b.w;
        h0[8] = c.x; h0[9] = c.y;
    }
    {
        float4 a = *(const float4*)&sUp[ib1 * 12];
        float4 b = *(const float4*)&sUp[ib1 * 12 + 4];
        float2 c = *(const float2*)&sUp[ib1 * 12 + 8];
        h1[0] = a.x; h1[1] = a.y; h1[2] = a.z; h1[3] = a.w;
        h1[4] = b.x; h1[5] = b.y; h1[6] = b.z; h1[7] = b.w;
        h1[8] = c.x; h1[9] = c.y;
    }
    #pragma unroll
    for (int k = 0; k < 25; ++k) {
        #pragma unroll
        for (int j = 0; j < 10; ++j) {
            const float w = W1[k * 10 + j];   // wave-uniform -> SGPR, shared by both edges
            h0[j] += f0[k] * w;
            h1[j] += f1[k] * w;
        }
    }
    #pragma unroll
    for (int j = 0; j < 10; ++j) {
        h0[j] = (h0[j] >= 0.f) ? h0[j] : 0.1f * h0[j];
        h1[j] = (h1[j] >= 0.f) ? h1[j] : 0.1f * h1[j];
    }

    // ---- layer 2, paired ----
    float o0[10], o1[10];
    #pragma unroll
    for (int j = 0; j < 10; ++j) { const float b2j = b2[j]; o0[j] = b2j; o1[j] = b2j; }
    #pragma unroll
    for (int k = 0; k < 10; ++k) {
        #pragma unroll
        for (int j = 0; j < 10; ++j) {
            const float w = W2[k * 10 + j];
            o0[j] += h0[k] * w;
            o1[j] += h1[k] * w;
        }
    }

    // ---- stores (guarded) ----
    if (e0 < E) {
        float2* po = (float2*)(out + (size_t)e0 * 10);
        #pragma unroll
        for (int i = 0; i < 5; ++i) { float2 v; v.x = o0[2 * i]; v.y = o0[2 * i + 1]; po[i] = v; }
    }
    if (e1 < E) {
        float2* po = (float2*)(out + (size_t)e1 * 10);
        #pragma unroll
        for (int i = 0; i < 5; ++i) { float2 v; v.x = o1[2 * i]; v.y = o1[2 * i + 1]; po[i] = v; }
    }
}

extern "C" void kernel_launch(void* const* d_in, const int* in_sizes, int n_in,
                              void* d_out, int out_size, void* d_ws, size_t ws_size,
                              hipStream_t stream) {
    const float* x_s      = (const float*)d_in[0];
    const float* x_t      = (const float*)d_in[1];
    const int*   ei       = (const int*)d_in[2];    // (2, E) flat: [src | tgt]
    const float* edge_att = (const float*)d_in[3];
    const float* u        = (const float*)d_in[4];
    const int*   batch_e  = (const int*)d_in[5];
    const float* W1       = (const float*)d_in[6];
    const float* b1       = (const float*)d_in[7];
    const float* W2       = (const float*)d_in[8];
    const float* b2       = (const float*)d_in[9];
    float* out = (float*)d_out;

    const int E   = in_sizes[5];
    const int N_S = in_sizes[0] / 10;
    const int N_T = in_sizes[1] / 5;
    const int blocks = (E + 511) / 512;   // 2 edges per thread

    const size_t need = (size_t)N_S * 16 * 4 + (size_t)N_T * 8 * 4;
    if (ws_size >= need) {
        float* xs_pad = (float*)d_ws;
        float* xt_pad = (float*)d_ws + (size_t)N_S * 16;
        const int n_s5 = N_S * 5;
        const int n_t5 = N_T * 5;
        const int n    = (n_s5 > n_t5 ? n_s5 : n_t5);
        pad_tables<<<(n + 255) / 256, 256, 0, stream>>>(x_s, x_t, xs_pad, xt_pad, n_s5, n_t5);
        edge_mlp<true><<<blocks, 256, 0, stream>>>(
            xs_pad, xt_pad, ei, ei + E, edge_att, u, batch_e,
            W1, b1, W2, b2, out, E);
    } else {
        edge_mlp<false><<<blocks, 256, 0, stream>>>(
            x_s, x_t, ei, ei + E, edge_att, u, batch_e,
            W1, b1, W2, b2, out, E);
    }
}